// Round 8
// baseline (30.876 us; speedup 1.0000x reference)
//
#include <hip/hip_runtime.h>

#define P 1024
#define NB 11
#define NBINS 1331          // 11^3
#define BATCH 8
#define TI 8                // i-rows per block
#define NIT (P / TI)        // 128 i-tiles (= main blocks) per batch

// force a (block-uniform) float into an SGPR
#define RFL(f) __uint_as_float(__builtin_amdgcn_readfirstlane(__float_as_uint(f)))

// One direction's histogram bin (validated in R4/R5, absmax 7.6e-6).
//   nii=|n_own|^2, sni=|n_own|, ao=n_own.delta, ax=n_other.delta,
//   ninj=ni.nj, t3=det[d,ni,nj] (direction-invariant), dd=|d|^2, rdd=rsq(dd)
__device__ __forceinline__ int bin_of(float nii, float sni, float ao, float ax,
                                      float ninj, float t3, float dd, float rdd) {
    float cvv = fmaxf(fmaf(dd, nii, -(ao * ao)), 0.0f);   // |d x n_own|^2 (Lagrange)
    float rs  = __builtin_amdgcn_rsqf(cvv);
    float alpha = t3 * rs;
    float scv = cvv * rs;                      // |cv|
    float phi = ao * rdd;
    float y   = fmaf(nii, ax, -(ao * ninj));   // cw . n_other
    float xx  = (sni * ninj) * scv;            // |cw| * (ni.nj)
    // cot|theta| against cot((2m-1)pi/11), m=1..5 (monotone decreasing)
    float tq  = xx * __builtin_amdgcn_rcpf(__builtin_fabsf(y));
    int kk = (tq <  3.40568625f) + (tq <  0.86650494f) + (tq < 0.14377830f)
           + (tq < -0.45668469f) + (tq < -1.55603037f);
    int ith = (y < 0.0f) ? 5 - kk : 5 + kk;    // in [0,10]
    int ia = min((int)fmaf(alpha, 5.5f, 5.5f), NB - 1);
    int ip = min((int)fmaf(phi,   5.5f, 5.5f), NB - 1);
    int bin = (ia * NB + ip) * NB + ith;
    if (bin < 0) bin += NBINS;                 // JAX wrap-once; caller drops OOB
    return bin;
}

// Unordered-pair kernel at R5's exact grid (128 x 8 blocks, 256 threads).
// Block T: i-tile T (8 rows, SGPR-resident) x circular j-window
// [8T+8, 8T+512) (tile distances 1..63, compute-once-emit-both), plus the
// 8x8 in-tile diagonal in the 8 spare lane-slots (directed), plus for T<64
// the distance-64 tile (covered by exactly one of {T, T+64}).
// Coverage: 128*(4096+3968+56) + 64*128 = 1,047,552 = 1024*1023 exactly.
__global__ __launch_bounds__(256, 8) void fpfh_main(const float* __restrict__ x,
                                                    int* __restrict__ part,
                                                    int npart) {
    __shared__ int shist[NBINS];

    const int t  = threadIdx.x;
    const int T  = blockIdx.x;
    const int b  = blockIdx.y;
    const int i0 = T * TI;
    const float* xb = x + b * (P * 6);

    for (int z = t; z < NBINS; z += 256) shist[z] = 0;

    // ---- 8 i-points into SGPRs (block-uniform) ----
    float PIX[TI], PIY[TI], PIZ[TI], NIX[TI], NIY[TI], NIZ[TI], NII[TI], SNI[TI];
    #pragma unroll
    for (int il = 0; il < TI; ++il) {
        const float* xi = xb + (i0 + il) * 6;
        PIX[il] = RFL(xi[0]); PIY[il] = RFL(xi[1]); PIZ[il] = RFL(xi[2]);
        NIX[il] = RFL(xi[3]); NIY[il] = RFL(xi[4]); NIZ[il] = RFL(xi[5]);
        float nii = fmaf(NIX[il], NIX[il], fmaf(NIY[il], NIY[il], NIZ[il] * NIZ[il]));
        NII[il] = RFL(nii);                              // |ni|^2
        SNI[il] = RFL(__builtin_amdgcn_sqrtf(nii));      // |ni|
    }

    // ---- this thread's j-points ----
    // pass 0: window offsets [0,256)  -> always unordered
    const int j0 = (i0 + 8 + t) & (P - 1);
    // pass 1: offsets [256,504) unordered; lanes t>=248 -> own-tile diagonal
    const bool uno1 = (t < 248);
    const int j1 = uno1 ? ((i0 + 264 + t) & (P - 1)) : (i0 + (t - 248));
    // cond pass (T<64, t<8): distance-64 tile, unordered
    const bool condA = (T < 64) && (t < 8);
    const int jc = i0 + 512 + t;                         // <= 1023, no wrap

    const float* xj0 = xb + j0 * 6;
    const float p0x = xj0[0], p0y = xj0[1], p0z = xj0[2];
    const float n0x = xj0[3], n0y = xj0[4], n0z = xj0[5];
    const float njj0 = fmaf(n0x, n0x, fmaf(n0y, n0y, n0z * n0z));
    const float snj0 = __builtin_amdgcn_sqrtf(njj0);

    const float* xj1 = xb + j1 * 6;
    const float p1x = xj1[0], p1y = xj1[1], p1z = xj1[2];
    const float n1x = xj1[3], n1y = xj1[4], n1z = xj1[5];
    const float njj1 = fmaf(n1x, n1x, fmaf(n1y, n1y, n1z * n1z));
    const float snj1 = __builtin_amdgcn_sqrtf(njj1);

    float pcx = 0, pcy = 0, pcz = 0, ncx = 0, ncy = 0, ncz = 0, njjc = 0, snjc = 0;
    if (condA) {
        const float* xjc = xb + jc * 6;
        pcx = xjc[0]; pcy = xjc[1]; pcz = xjc[2];
        ncx = xjc[3]; ncy = xjc[4]; ncz = xjc[5];
        njjc = fmaf(ncx, ncx, fmaf(ncy, ncy, ncz * ncz));
        snjc = __builtin_amdgcn_sqrtf(njjc);
    }

    __syncthreads();   // shist zeroed

    // BODY: shared math once, emit center-i bin (and center-j bin if UNO).
#define BODY(JV, PX, PY, PZ, NX, NY, NZ, NJJ, SNJ, UNO)                        \
    {                                                                          \
        const float dx = PX - PIX[il];                                         \
        const float dy = PY - PIY[il];                                         \
        const float dz = PZ - PIZ[il];                                         \
        const float dd   = fmaf(dx, dx, fmaf(dy, dy, dz * dz));                \
        const float nid  = fmaf(NIX[il], dx, fmaf(NIY[il], dy, NIZ[il] * dz)); \
        const float njd  = fmaf(NX, dx, fmaf(NY, dy, NZ * dz));                \
        const float ninj = fmaf(NIX[il], NX, fmaf(NIY[il], NY, NIZ[il] * NZ)); \
        const float cvx  = fmaf(dy, NIZ[il], -(dz * NIY[il]));                 \
        const float cvy  = fmaf(dz, NIX[il], -(dx * NIZ[il]));                 \
        const float cvz  = fmaf(dx, NIY[il], -(dy * NIX[il]));                 \
        const float t3   = fmaf(cvx, NX, fmaf(cvy, NY, cvz * NZ));             \
        const float rdd  = __builtin_amdgcn_rsqf(dd);                          \
        const int bin1 = bin_of(NII[il], SNI[il],  nid,  njd, ninj, t3, dd, rdd); \
        const bool e1 = ((UNO) || (JV) != i0 + il) && ((unsigned)bin1 < (unsigned)NBINS); \
        if (e1) atomicAdd(&shist[bin1], 1);                                    \
        if (UNO) {                                                             \
            const int bin2 = bin_of(NJJ, SNJ, -njd, -nid, ninj, t3, dd, rdd);  \
            if ((unsigned)bin2 < (unsigned)NBINS) atomicAdd(&shist[bin2], 1);  \
        }                                                                      \
    }

    #pragma unroll
    for (int il = 0; il < TI; ++il)
        BODY(j0, p0x, p0y, p0z, n0x, n0y, n0z, njj0, snj0, true)

    #pragma unroll
    for (int il = 0; il < TI; ++il)
        BODY(j1, p1x, p1y, p1z, n1x, n1y, n1z, njj1, snj1, uno1)

    if (condA) {
        #pragma unroll
        for (int il = 0; il < TI; ++il)
            BODY(jc, pcx, pcy, pcz, ncx, ncy, ncz, njjc, snjc, true)
    }
#undef BODY
    __syncthreads();

    if (npart == NIT) {
        // exclusive slot per block: plain stores, no zeroing needed
        int* slot = part + (b * NIT + blockIdx.x) * NBINS;
        for (int z = t; z < NBINS; z += 256) slot[z] = shist[z];
    } else {
        // shared slots (pre-zeroed by host memset): int atomics, deterministic
        int* slot = part + (b * npart + (blockIdx.x % npart)) * NBINS;
        for (int z = t; z < NBINS; z += 256) {
            int c = shist[z];
            if (c) atomicAdd(&slot[z], c);
        }
    }
}

// 4 threads per (batch, bin); each sums partials k = q, q+4, ... (fixed-order
// int adds -> deterministic), then two shfl_xor combines; q==0 lane stores.
__global__ __launch_bounds__(256) void fpfh_reduce(const int* __restrict__ part,
                                                   float* __restrict__ out,
                                                   int npart) {
    const int tid = blockIdx.x * 256 + threadIdx.x;
    const int o   = tid >> 2;            // output index = b*NBINS + bin
    const int q   = tid & 3;
    int s = 0;
    if (o < BATCH * NBINS) {
        const int b   = o / NBINS;
        const int bin = o - b * NBINS;
        const int* p  = part + (size_t)b * npart * NBINS + bin;
        for (int k = q; k < npart; k += 4)
            s += p[(size_t)k * NBINS];
    }
    s += __shfl_xor(s, 1);
    s += __shfl_xor(s, 2);
    if (q == 0 && o < BATCH * NBINS)
        out[o] = (float)s * (1.0f / 1047552.0f);   // / (P*(P-1))
}

extern "C" void kernel_launch(void* const* d_in, const int* in_sizes, int n_in,
                              void* d_out, int out_size, void* d_ws, size_t ws_size,
                              hipStream_t stream) {
    const float* x = (const float*)d_in[0];
    float* out = (float*)d_out;
    int* part  = (int*)d_ws;

    const size_t slot_bytes = (size_t)BATCH * NBINS * sizeof(int);   // 42,592 B
    const size_t need_excl  = slot_bytes * NIT;                      // ~5.45 MB
    int npart;
    if (ws_size >= need_excl) {
        npart = NIT;                  // exclusive slots: no zeroing, no atomics
    } else {
        npart = (int)(ws_size / slot_bytes);
        if (npart < 1)   npart = 1;
        if (npart > NIT) npart = NIT;
        hipMemsetAsync(d_ws, 0, slot_bytes * npart, stream);   // graph-legal
    }

    dim3 grid(NIT, BATCH);            // 128 x 8 = 1024 blocks of 256 threads
    fpfh_main<<<grid, 256, 0, stream>>>(x, part, npart);

    const int nThreads = BATCH * NBINS * 4;
    fpfh_reduce<<<(nThreads + 255) / 256, 256, 0, stream>>>(part, out, npart);
}

// Round 9
// 28.754 us; speedup vs baseline: 1.0738x; 1.0738x over previous
//
#include <hip/hip_runtime.h>

#define P 1024
#define NB 11
#define NBINS 1331          // 11^3
#define BATCH 8
#define TI 8                // i-rows per block
#define NIT (P / TI)        // 128 i-tiles (= main blocks) per batch
#define NCOPY 4             // LDS sub-histogram replicas
#define CSTRIDE 1352        // ints; 1352 % 32 == 8 -> copies bank-shifted by 8

// force a (block-uniform) float into an SGPR
#define RFL(f) __uint_as_float(__builtin_amdgcn_readfirstlane(__float_as_uint(f)))

// Directed-pair kernel, R5 structure + 4-way replicated LDS histogram to cut
// same-address atomic serialization. Each block: 8-row i-tile (SGPR-resident)
// x all 1024 j (4 register-prefetched tiles of 256).
__global__ __launch_bounds__(256, 8) void fpfh_main(const float* __restrict__ x,
                                                    int* __restrict__ part,
                                                    int npart) {
    __shared__ int shist[NCOPY * CSTRIDE];

    const int t  = threadIdx.x;
    const int b  = blockIdx.y;
    const int i0 = blockIdx.x * TI;
    const float* xb = x + b * (P * 6);
    const int hbase = (t & (NCOPY - 1)) * CSTRIDE;   // this thread's replica

    for (int z = t; z < NCOPY * CSTRIDE; z += 256) shist[z] = 0;

    // ---- 8 i-points into SGPRs (block-uniform) ----
    float PIX[TI], PIY[TI], PIZ[TI], NIX[TI], NIY[TI], NIZ[TI], NII[TI], SNI[TI];
    #pragma unroll
    for (int il = 0; il < TI; ++il) {
        const float* xi = xb + (i0 + il) * 6;
        PIX[il] = RFL(xi[0]); PIY[il] = RFL(xi[1]); PIZ[il] = RFL(xi[2]);
        NIX[il] = RFL(xi[3]); NIY[il] = RFL(xi[4]); NIZ[il] = RFL(xi[5]);
        float nii = fmaf(NIX[il], NIX[il], fmaf(NIY[il], NIY[il], NIZ[il] * NIZ[il]));
        NII[il] = RFL(nii);                              // |ni|^2
        SNI[il] = RFL(__builtin_amdgcn_sqrtf(nii));      // |ni|
    }

    // ---- prefetch this thread's 4 j-points (coalesced, L1/L2-resident) ----
    float pjx[4], pjy[4], pjz[4], njx[4], njy[4], njz[4];
    #pragma unroll
    for (int jt = 0; jt < 4; ++jt) {
        const float* xj = xb + (jt * 256 + t) * 6;
        pjx[jt] = xj[0]; pjy[jt] = xj[1]; pjz[jt] = xj[2];
        njx[jt] = xj[3]; njy[jt] = xj[4]; njz[jt] = xj[5];
    }

    __syncthreads();   // shist zeroed

    #pragma unroll
    for (int jt = 0; jt < 4; ++jt) {
        const int j = jt * 256 + t;

        #pragma unroll
        for (int il = 0; il < TI; ++il) {
            // delta = pos_j - pos_i
            const float dx = pjx[jt] - PIX[il];
            const float dy = pjy[jt] - PIY[il];
            const float dz = pjz[jt] - PIZ[il];

            const float dd    = fmaf(dx, dx, fmaf(dy, dy, dz * dz));
            const float nid   = fmaf(NIX[il], dx, fmaf(NIY[il], dy, NIZ[il] * dz));
            const float nidnj = fmaf(NIX[il], njx[jt],
                                fmaf(NIY[il], njy[jt], NIZ[il] * njz[jt]));
            const float ddnj  = fmaf(dx, njx[jt], fmaf(dy, njy[jt], dz * njz[jt]));

            // cv = delta x ni ;  cv . nj
            const float cvx = fmaf(dy, NIZ[il], -(dz * NIY[il]));
            const float cvy = fmaf(dz, NIX[il], -(dx * NIZ[il]));
            const float cvz = fmaf(dx, NIY[il], -(dy * NIX[il]));
            const float cvdnj = fmaf(cvx, njx[jt],
                                fmaf(cvy, njy[jt], cvz * njz[jt]));

            // |cv|^2 = dd*|ni|^2 - (ni.d)^2   (Lagrange; cv ⟂ ni)
            float cvv = fmaxf(fmaf(dd, NII[il], -(nid * nid)), 0.0f);
            const float rs    = __builtin_amdgcn_rsqf(cvv);
            const float alpha = cvdnj * rs;
            const float scv   = cvv * rs;                 // |cv|

            const float phi = nid * __builtin_amdgcn_rsqf(dd);

            // theta = atan2(y, x): y = cw.nj = |ni|^2(d.nj) - (ni.d)(ni.nj),
            //                      x = |ni||cv| * (ni.nj)
            // binned via cot|theta| against cot((2m-1)pi/11), m=1..5
            const float y_t = fmaf(NII[il], ddnj, -(nid * nidnj));
            const float x_t = (SNI[il] * nidnj) * scv;
            const float tq  = x_t * __builtin_amdgcn_rcpf(__builtin_fabsf(y_t));
            int kk = (tq <  3.40568625f) + (tq <  0.86650494f) + (tq < 0.14377830f)
                   + (tq < -0.45668469f) + (tq < -1.55603037f);
            const int ith = (y_t < 0.0f) ? 5 - kk : 5 + kk;   // in [0,10]

            int ia = min((int)fmaf(alpha, 5.5f, 5.5f), NB - 1);
            int ip = min((int)fmaf(phi,   5.5f, 5.5f), NB - 1);

            int bin = (ia * NB + ip) * NB + ith;
            if (bin < 0) bin += NBINS;               // JAX wrap-once
            if ((j != i0 + il) && ((unsigned)bin < (unsigned)NBINS))
                atomicAdd(&shist[hbase + bin], 1);   // still-OOB dropped
        }
    }
    __syncthreads();

    if (npart == NIT) {
        // exclusive slot per block: plain stores, no zeroing needed
        int* slot = part + (b * NIT + blockIdx.x) * NBINS;
        for (int z = t; z < NBINS; z += 256)
            slot[z] = shist[z] + shist[CSTRIDE + z]
                    + shist[2 * CSTRIDE + z] + shist[3 * CSTRIDE + z];
    } else {
        // shared slots (pre-zeroed by host memset): int atomics, deterministic
        int* slot = part + (b * npart + (blockIdx.x % npart)) * NBINS;
        for (int z = t; z < NBINS; z += 256) {
            int c = shist[z] + shist[CSTRIDE + z]
                  + shist[2 * CSTRIDE + z] + shist[3 * CSTRIDE + z];
            if (c) atomicAdd(&slot[z], c);
        }
    }
}

// 8 threads per (batch, bin); each sums partials k = q, q+8, ... (fixed-order
// int adds -> deterministic), then three shfl_xor combines; q==0 lane stores.
__global__ __launch_bounds__(256) void fpfh_reduce(const int* __restrict__ part,
                                                   float* __restrict__ out,
                                                   int npart) {
    const int tid = blockIdx.x * 256 + threadIdx.x;
    const int o   = tid >> 3;            // output index = b*NBINS + bin
    const int q   = tid & 7;
    int s = 0;
    if (o < BATCH * NBINS) {
        const int b   = o / NBINS;
        const int bin = o - b * NBINS;
        const int* p  = part + (size_t)b * npart * NBINS + bin;
        for (int k = q; k < npart; k += 8)
            s += p[(size_t)k * NBINS];
    }
    s += __shfl_xor(s, 1);
    s += __shfl_xor(s, 2);
    s += __shfl_xor(s, 4);
    if (q == 0 && o < BATCH * NBINS)
        out[o] = (float)s * (1.0f / 1047552.0f);   // / (P*(P-1))
}

extern "C" void kernel_launch(void* const* d_in, const int* in_sizes, int n_in,
                              void* d_out, int out_size, void* d_ws, size_t ws_size,
                              hipStream_t stream) {
    const float* x = (const float*)d_in[0];
    float* out = (float*)d_out;
    int* part  = (int*)d_ws;

    const size_t slot_bytes = (size_t)BATCH * NBINS * sizeof(int);   // 42,592 B
    const size_t need_excl  = slot_bytes * NIT;                      // ~5.45 MB
    int npart;
    if (ws_size >= need_excl) {
        npart = NIT;                  // exclusive slots: no zeroing, no atomics
    } else {
        npart = (int)(ws_size / slot_bytes);
        if (npart < 1)   npart = 1;
        if (npart > NIT) npart = NIT;
        hipMemsetAsync(d_ws, 0, slot_bytes * npart, stream);   // graph-legal
    }

    dim3 grid(NIT, BATCH);            // 128 x 8 = 1024 blocks of 256 threads
    fpfh_main<<<grid, 256, 0, stream>>>(x, part, npart);

    const int nThreads = BATCH * NBINS * 8;
    fpfh_reduce<<<(nThreads + 255) / 256, 256, 0, stream>>>(part, out, npart);
}